// Round 6
// baseline (136.595 us; speedup 1.0000x reference)
//
#include <hip/hip_runtime.h>

#define B_DIM 4096
#define I_DIM 1024
#define O_DIM 1024
#define ON_DIM 4096      // O * N fan-in columns
#define TILE_HALFS 4096  // one 128(m) x 32(k) fp16 tile image = 8 KB
                         // image order: [kb8(4)][m(128)][j(8)] halfs

typedef _Float16 half8  __attribute__((ext_vector_type(8)));
typedef _Float16 half4_t __attribute__((ext_vector_type(4)));
typedef float    floatx4 __attribute__((ext_vector_type(4)));

// ---------------------------------------------------------------------------
// Kernel A: per-row softmax stats (max, 1/sum) — one wave per row.
// ---------------------------------------------------------------------------
__global__ __launch_bounds__(256)
void ltn_stats(const float* __restrict__ logits, float2* __restrict__ stats) {
  const int t = threadIdx.x, lane = t & 63, wv = t >> 6;
  const int row = blockIdx.x * 4 + wv;
  const float4* src = (const float4*)(logits + (size_t)row * I_DIM);
  float4 v[4];
#pragma unroll
  for (int j = 0; j < 4; j++) v[j] = src[j * 64 + lane];
  float m = -1e30f;
#pragma unroll
  for (int j = 0; j < 4; j++)
    m = fmaxf(m, fmaxf(fmaxf(v[j].x, v[j].y), fmaxf(v[j].z, v[j].w)));
#pragma unroll
  for (int off = 1; off < 64; off <<= 1) m = fmaxf(m, __shfl_xor(m, off));
  float s = 0.0f;
#pragma unroll
  for (int j = 0; j < 4; j++) {
    s += __expf(v[j].x - m) + __expf(v[j].y - m)
       + __expf(v[j].z - m) + __expf(v[j].w - m);
  }
#pragma unroll
  for (int off = 1; off < 64; off <<= 1) s += __shfl_xor(s, off);
  if (lane == 0) stats[row] = make_float2(m, 1.0f / s);
}

// ---------------------------------------------------------------------------
// Kernel B: fully-coalesced tile writer.
//  blocks [0,1024):    wt tile (nb,kb): softmax-normalize 128x32 logits block
//  blocks [1024,2048): xt tile (mb,kt): fp32->fp16 convert 128x32 x block
// ---------------------------------------------------------------------------
__global__ __launch_bounds__(256)
void ltn_tile(const float* __restrict__ logits, const float* __restrict__ x,
              const float2* __restrict__ stats,
              _Float16* __restrict__ wt, _Float16* __restrict__ xt) {
  const int t  = threadIdx.x;
  const int nn = t >> 1;        // row within 128-tile
  const int hf = t & 1;         // which 16-k half of the 32-k tile
  if (blockIdx.x < 1024) {
    const int nb = blockIdx.x >> 5, kb = blockIdx.x & 31;
    const int row = nb * 128 + nn;
    const float2 st = stats[row];
    const float4* src = (const float4*)(logits + (size_t)row * I_DIM + kb * 32 + hf * 16);
    const float4 a = src[0], b = src[1], c = src[2], d = src[3];
    half8 h0, h1;
    h0[0] = (_Float16)(__expf(a.x - st.x) * st.y);
    h0[1] = (_Float16)(__expf(a.y - st.x) * st.y);
    h0[2] = (_Float16)(__expf(a.z - st.x) * st.y);
    h0[3] = (_Float16)(__expf(a.w - st.x) * st.y);
    h0[4] = (_Float16)(__expf(b.x - st.x) * st.y);
    h0[5] = (_Float16)(__expf(b.y - st.x) * st.y);
    h0[6] = (_Float16)(__expf(b.z - st.x) * st.y);
    h0[7] = (_Float16)(__expf(b.w - st.x) * st.y);
    h1[0] = (_Float16)(__expf(c.x - st.x) * st.y);
    h1[1] = (_Float16)(__expf(c.y - st.x) * st.y);
    h1[2] = (_Float16)(__expf(c.z - st.x) * st.y);
    h1[3] = (_Float16)(__expf(c.w - st.x) * st.y);
    h1[4] = (_Float16)(__expf(d.x - st.x) * st.y);
    h1[5] = (_Float16)(__expf(d.y - st.x) * st.y);
    h1[6] = (_Float16)(__expf(d.z - st.x) * st.y);
    h1[7] = (_Float16)(__expf(d.w - st.x) * st.y);
    _Float16* base = wt + ((size_t)nb * 32 + kb) * TILE_HALFS + (hf * 2) * 1024 + nn * 8;
    *(half8*)base = h0;
    *(half8*)(base + 1024) = h1;
  } else {
    const int bid = blockIdx.x - 1024;
    const int mb = bid >> 5, kt = bid & 31;
    const int row = mb * 128 + nn;
    const float4* src = (const float4*)(x + (size_t)row * I_DIM + kt * 32 + hf * 16);
    const float4 a = src[0], b = src[1], c = src[2], d = src[3];
    half8 h0, h1;
    h0[0] = (_Float16)a.x; h0[1] = (_Float16)a.y; h0[2] = (_Float16)a.z; h0[3] = (_Float16)a.w;
    h0[4] = (_Float16)b.x; h0[5] = (_Float16)b.y; h0[6] = (_Float16)b.z; h0[7] = (_Float16)b.w;
    h1[0] = (_Float16)c.x; h1[1] = (_Float16)c.y; h1[2] = (_Float16)c.z; h1[3] = (_Float16)c.w;
    h1[4] = (_Float16)d.x; h1[5] = (_Float16)d.y; h1[6] = (_Float16)d.z; h1[7] = (_Float16)d.w;
    _Float16* base = xt + ((size_t)mb * 32 + kt) * TILE_HALFS + (hf * 2) * 1024 + nn * 8;
    *(half8*)base = h0;
    *(half8*)(base + 1024) = h1;
  }
}

// ---------------------------------------------------------------------------
// GEMM + sigmoid + 16-corner LUT.  R5/R6: BK=64 on the best-measured loop.
// Post-mortem R0-R4: four schedules x {BK=32} all pinned at 55-58us GEMM
// (~610 TF), insensitive to vmcnt discipline, phase granularity, and
// blocks/CU. Modeled LDS-pipe (~1000cy) + MFMA (~310cy/SIMD) per k-step is
// far below the measured ~4100cy/k-step -> the surviving hypothesis is a
// fixed per-sync-event cost (barrier skew + queue drain + ramp). Only knob
// untouched so far: EVENT COUNT. BK=64 halves it (16 steps) and doubles the
// MFMA work per event (64 MFMA/wave), so the end-of-step vmcnt(0) drain is
// issued >=1200cy after its loads (nearly free) and happens half as often.
// 256x256 tile, 8 waves (4x2), 2 x 64KB double-buffer = 128 KB, 1 block/CU.
// ---------------------------------------------------------------------------
__global__ __launch_bounds__(512, 2)
void ltn_gemm_lut(const _Float16* __restrict__ xt,   // tiles [32*32][TILE_HALFS]
                  const _Float16* __restrict__ wt,
                  const float* __restrict__ lut,     // [O][16]
                  float* __restrict__ out) {         // [B][O]
  // per buf: A = [kk(2)][mtile(2)][kb8(4)][128][8] = 16384 halfs, B same.
  __shared__ _Float16 sm[2 * 32768];

  const int tid  = threadIdx.x;
  const int lane = tid & 63;
  const int wv   = tid >> 6;     // 0..7
  const int wr   = wv >> 1;      // row-wave 0..3  (64 rows each)
  const int wc   = wv & 1;       // col-wave 0..1  (128 cols each)

  // XCD-chunked swizzle (FETCH_SIZE -33% in R1; kept).
  const int id  = blockIdx.x;    // 0..255
  const int xcd = id & 7;
  const int li  = id >> 3;       // 0..31
  const int mb  = (xcd & 3) * 4 + (li & 3);
  const int nb  = (xcd >> 2) * 8 + (li >> 2);

  const int fm = lane & 15;
  const int kq = lane >> 4;

  const size_t baseA = (size_t)(mb * 2) * 32 * TILE_HALFS;
  const size_t baseB = (size_t)(nb * 2) * 32 * TILE_HALFS;

  floatx4 acc[4][8];
#pragma unroll
  for (int i = 0; i < 4; i++)
#pragma unroll
    for (int j = 0; j < 8; j++) acc[i][j] = (floatx4)0.0f;

  // One BK=64 k-tile = 64 chunks of 1KB (32 A + 32 B); wave wv stages 8.
  // A chunk ca: kk=ca>>4, cc=ca&15, tl=cc>>3 (128-row tile), sub=cc&7.
  // LDS: bufOff + ca*512 (A), bufOff + 16384 + cb*512 (B) — linear images.
  auto stage = [&](int bufOff /*halfs*/, int kt) {
#pragma unroll
    for (int s = 0; s < 8; s++) {
      const int c = wv * 8 + s;          // 0..63, wave-uniform
      const _Float16* g;
      int dst;
      if (c < 32) {
        const int kk = c >> 4, cc = c & 15, tl = cc >> 3, sub = cc & 7;
        g = xt + baseA + (size_t)(tl * 32 + kt * 2 + kk) * TILE_HALFS
              + sub * 512 + lane * 8;
        dst = bufOff + c * 512;
      } else {
        const int cb = c - 32;
        const int kk = cb >> 4, cc = cb & 15, tl = cc >> 3, sub = cc & 7;
        g = wt + baseB + (size_t)(tl * 32 + kt * 2 + kk) * TILE_HALFS
              + sub * 512 + lane * 8;
        dst = bufOff + 16384 + cb * 512;
      }
      __builtin_amdgcn_global_load_lds(
          (const __attribute__((address_space(1))) void*)g,
          (__attribute__((address_space(3))) void*)(sm + dst), 16, 0, 0);
    }
  };

  auto compute = [&](int bufOff) {
#pragma unroll
    for (int kk = 0; kk < 2; kk++) {
      half8 af[4], bf[8];
#pragma unroll
      for (int f = 0; f < 4; f++)
        af[f] = *(const half8*)&sm[bufOff + kk * 8192 + (wr >> 1) * 4096
                                   + kq * 1024
                                   + ((wr & 1) * 64 + f * 16 + fm) * 8];
#pragma unroll
      for (int g = 0; g < 8; g++)
        bf[g] = *(const half8*)&sm[bufOff + 16384 + kk * 8192 + wc * 4096
                                   + kq * 1024 + (g * 16 + fm) * 8];
      __builtin_amdgcn_s_setprio(1);
#pragma unroll
      for (int mt = 0; mt < 4; mt++)
#pragma unroll
        for (int nt = 0; nt < 8; nt++)
          acc[mt][nt] = __builtin_amdgcn_mfma_f32_16x16x32_f16(
              af[mt], bf[nt], acc[mt][nt], 0, 0, 0);
      __builtin_amdgcn_s_setprio(0);
    }
  };

  stage(0, 0);
  asm volatile("s_waitcnt vmcnt(0)" ::: "memory");
  __builtin_amdgcn_s_barrier();

  int buf = 0;
#pragma unroll 1
  for (int kt = 0; kt < 16; kt++) {
    const int bo = buf * 32768;
    // Issue next-tile stage FIRST (into the buffer whose reads all completed
    // before the barrier that started this iteration) — WAR-safe.
    if (kt + 1 < 16) stage((buf ^ 1) * 32768, kt + 1);
    __builtin_amdgcn_sched_barrier(0);
    compute(bo);                          // ~64 MFMA/wave window hides loads
    if (kt + 1 < 16) {
      asm volatile("s_waitcnt vmcnt(0)" ::: "memory");
      __builtin_amdgcn_s_barrier();
    }
    buf ^= 1;
  }

  // ---- fused epilogue: sigmoid -> gather 4 fan-in values -> LUT contraction
  // C/D layout: col = lane&15, row = (lane>>4)*4 + reg. The 4 n-values of one
  // o live in 4 consecutive lanes.
#pragma unroll
  for (int nt = 0; nt < 8; nt++) {
    const int o = (nb * 256 + wc * 128 + nt * 16 + fm) >> 2;
    const float4* lt4 = (const float4*)(lut + (size_t)o * 16);
    const float4 L0 = lt4[0], L1 = lt4[1], L2 = lt4[2], L3 = lt4[3];
#pragma unroll
    for (int mt = 0; mt < 4; mt++) {
#pragma unroll
      for (int r = 0; r < 4; r++) {
        const float v  = acc[mt][nt][r];
        const float sv = 1.0f / (1.0f + __expf(-v));
        const float s1 = __shfl_down(sv, 1);
        const float s2 = __shfl_down(sv, 2);
        const float s3 = __shfl_down(sv, 3);
        if ((lane & 3) == 0) {
          const float s0 = sv;
          const float a0 = L0.x + (L2.x - L0.x) * s3;
          const float a1 = L0.y + (L2.y - L0.y) * s3;
          const float a2 = L0.z + (L2.z - L0.z) * s3;
          const float a3 = L0.w + (L2.w - L0.w) * s3;
          const float a4 = L1.x + (L3.x - L1.x) * s3;
          const float a5 = L1.y + (L3.y - L1.y) * s3;
          const float a6 = L1.z + (L3.z - L1.z) * s3;
          const float a7 = L1.w + (L3.w - L1.w) * s3;
          const float b0 = a0 + (a4 - a0) * s2;
          const float b1 = a1 + (a5 - a1) * s2;
          const float b2 = a2 + (a6 - a2) * s2;
          const float b3 = a3 + (a7 - a3) * s2;
          const float c0 = b0 + (b2 - b0) * s1;
          const float c1 = b1 + (b3 - b1) * s1;
          const float res = c0 + (c1 - c0) * s0;
          const int row = mb * 256 + wr * 64 + mt * 16 + (lane >> 4) * 4 + r;
          out[(size_t)row * O_DIM + o] = res;
        }
      }
    }
  }
}

// ---------------------------------------------------------------------------
extern "C" void kernel_launch(void* const* d_in, const int* in_sizes, int n_in,
                              void* d_out, int out_size, void* d_ws, size_t ws_size,
                              hipStream_t stream) {
  const float* x      = (const float*)d_in[0];  // (B, I)
  const float* logits = (const float*)d_in[1];  // (O, N, I)
  const float* lut    = (const float*)d_in[2];  // (O, 16)
  float* out          = (float*)d_out;          // (B, O)

  _Float16* wt = (_Float16*)d_ws;                                  // 8 MB tiled
  _Float16* xt = (_Float16*)d_ws + (size_t)ON_DIM * I_DIM;         // 8 MB tiled
  // stats scratch parked in d_out (32 KB); GEMM fully overwrites d_out later.
  float2* stats = (float2*)d_out;

  ltn_stats<<<1024, 256, 0, stream>>>(logits, stats);
  ltn_tile<<<2048, 256, 0, stream>>>(logits, x, stats, wt, xt);
  ltn_gemm_lut<<<256, 512, 0, stream>>>(xt, wt, lut, out);
}

// Round 7
// 132.825 us; speedup vs baseline: 1.0284x; 1.0284x over previous
//
#include <hip/hip_runtime.h>

#define B_DIM 4096
#define I_DIM 1024
#define O_DIM 1024
#define ON_DIM 4096      // O * N fan-in columns
#define TILE_HALFS 4096  // one 128(m) x 32(k) fp16 tile image = 8 KB
                         // image order: [kb8(4)][m(128)][j(8)] halfs

typedef _Float16 half8  __attribute__((ext_vector_type(8)));
typedef _Float16 half4_t __attribute__((ext_vector_type(4)));
typedef float    floatx4 __attribute__((ext_vector_type(4)));

// ---------------------------------------------------------------------------
// Kernel P (R7): fused prep — 2 launches total instead of 3.
//  blocks [0,1024):    wt path, FUSED softmax: 4 whole logits rows per block
//                      (1 row/wave). Read row once (4KB contiguous/wave),
//                      stats in-wave, normalize in regs, transpose via LDS,
//                      store 64B-contiguous half8 runs into the tile image.
//  blocks [1024,2048): xt path (unchanged from R0): fp32->fp16 128x32 block,
//                      512B-contiguous wave stores.
// Saves: ltn_stats dispatch + one launch gap + one full logits read.
// ---------------------------------------------------------------------------
__global__ __launch_bounds__(256)
void ltn_prep(const float* __restrict__ logits, const float* __restrict__ x,
              _Float16* __restrict__ wt, _Float16* __restrict__ xt) {
  const int t = threadIdx.x;
  if (blockIdx.x < 1024) {
    // padded [4][1040]: 16B-aligned rows (2080B), read-phase conflicts ~4-way
    __shared__ _Float16 lbuf[4][1040];
    const int lane = t & 63, wv = t >> 6;
    const int row  = blockIdx.x * 4 + wv;          // ON row, 4-aligned base
    const int nb   = row >> 7;
    const int nnB  = (blockIdx.x * 4) & 127;       // base m within 128-tile
    const float4* s4 = (const float4*)(logits + (size_t)row * I_DIM);
    float4 v[4];
#pragma unroll
    for (int j = 0; j < 4; j++) v[j] = s4[lane * 4 + j];  // 64B/lane contig
    float m = -1e30f;
#pragma unroll
    for (int j = 0; j < 4; j++)
      m = fmaxf(m, fmaxf(fmaxf(v[j].x, v[j].y), fmaxf(v[j].z, v[j].w)));
#pragma unroll
    for (int off = 1; off < 64; off <<= 1) m = fmaxf(m, __shfl_xor(m, off));
    // p = exp(v-m); sum-reduce; normalize in regs
    float s = 0.0f;
#pragma unroll
    for (int j = 0; j < 4; j++) {
      v[j].x = __expf(v[j].x - m); v[j].y = __expf(v[j].y - m);
      v[j].z = __expf(v[j].z - m); v[j].w = __expf(v[j].w - m);
      s += v[j].x + v[j].y + v[j].z + v[j].w;
    }
#pragma unroll
    for (int off = 1; off < 64; off <<= 1) s += __shfl_xor(s, off);
    const float inv = 1.0f / s;
#pragma unroll
    for (int j = 0; j < 4; j++) {
      half4_t h;
      h[0] = (_Float16)(v[j].x * inv); h[1] = (_Float16)(v[j].y * inv);
      h[2] = (_Float16)(v[j].z * inv); h[3] = (_Float16)(v[j].w * inv);
      *(half4_t*)&lbuf[wv][lane * 16 + j * 4] = h;   // k = lane*16+j*4..+3
    }
    __syncthreads();
    // store phase: 512 half8 units = (kb 0..31) x (kb8 0..3) x (nn4 0..3);
    // unit u: addr = img(kb) + kb8*1024 + (nnB+nn4)*8 — consecutive nn4 are
    // 16B-adjacent => 64B contiguous per (kb,kb8) across 4 rows.
#pragma unroll
    for (int p = 0; p < 2; p++) {
      const int u   = t + p * 256;
      const int nn4 = u & 3;
      const int kb8 = (u >> 2) & 3;
      const int kb  = u >> 4;
      const half8 h = *(const half8*)&lbuf[nn4][kb * 32 + kb8 * 8];
      _Float16* dst = wt + ((size_t)nb * 32 + kb) * TILE_HALFS
                    + kb8 * 1024 + (nnB + nn4) * 8;
      *(half8*)dst = h;
    }
  } else {
    const int bid = blockIdx.x - 1024;
    const int nn = t >> 1;        // row within 128-tile
    const int hf = t & 1;         // which 16-k half of the 32-k tile
    const int mb = bid >> 5, kt = bid & 31;
    const int row = mb * 128 + nn;
    const float4* src = (const float4*)(x + (size_t)row * I_DIM + kt * 32 + hf * 16);
    const float4 a = src[0], b = src[1], c = src[2], d = src[3];
    half8 h0, h1;
    h0[0] = (_Float16)a.x; h0[1] = (_Float16)a.y; h0[2] = (_Float16)a.z; h0[3] = (_Float16)a.w;
    h0[4] = (_Float16)b.x; h0[5] = (_Float16)b.y; h0[6] = (_Float16)b.z; h0[7] = (_Float16)b.w;
    h1[0] = (_Float16)c.x; h1[1] = (_Float16)c.y; h1[2] = (_Float16)c.z; h1[3] = (_Float16)c.w;
    h1[4] = (_Float16)d.x; h1[5] = (_Float16)d.y; h1[6] = (_Float16)d.z; h1[7] = (_Float16)d.w;
    _Float16* base = xt + ((size_t)mb * 32 + kt) * TILE_HALFS + (hf * 2) * 1024 + nn * 8;
    *(half8*)base = h0;
    *(half8*)(base + 1024) = h1;
  }
}

// ---------------------------------------------------------------------------
// GEMM + sigmoid + 16-corner LUT — FROZEN at R1's best-measured variant
// (54.8us). Post-mortem R0-R6: five schedules {2-buf drain, 3-buf counted
// vmcnt, 8-phase lockstep, 128^2 x 4 blocks/CU, BK=64} all 54.8-58.2us,
// MfmaUtil 23-25% -> schedule-insensitive; GEMM declared locally converged
// at ~610 TF this session. 256x256 tile, 8 waves (4x2), BK=32, triple-
// buffered 96KB LDS, 2-deep counted vmcnt(4), XCD-chunked swizzle.
// ---------------------------------------------------------------------------
__global__ __launch_bounds__(512, 2)
void ltn_gemm_lut(const _Float16* __restrict__ xt,   // tiles [32*32][TILE_HALFS]
                  const _Float16* __restrict__ wt,
                  const float* __restrict__ lut,     // [O][16]
                  float* __restrict__ out) {         // [B][O]
  __shared__ _Float16 sm[3 * 16384];   // 3 x (A 16KB | B 16KB)

  const int tid  = threadIdx.x;
  const int lane = tid & 63;
  const int wv   = tid >> 6;     // 0..7
  const int wr   = wv >> 1;      // row-wave 0..3  (64 rows each)
  const int wc   = wv & 1;       // col-wave 0..1  (128 cols each)

  const int id  = blockIdx.x;    // 0..255
  const int xcd = id & 7;
  const int li  = id >> 3;       // 0..31
  const int mb  = (xcd & 3) * 4 + (li & 3);
  const int nb  = (xcd >> 2) * 8 + (li >> 2);

  const int fm = lane & 15;
  const int kq = lane >> 4;

  const size_t baseA = (size_t)(mb * 2) * 32 * TILE_HALFS;
  const size_t baseB = (size_t)(nb * 2) * 32 * TILE_HALFS;

  floatx4 acc[4][8];
#pragma unroll
  for (int i = 0; i < 4; i++)
#pragma unroll
    for (int j = 0; j < 8; j++) acc[i][j] = (floatx4)0.0f;

  auto stage = [&](int bufOff /*halfs*/, int kt) {
#pragma unroll
    for (int s = 0; s < 4; s++) {
      const int c   = wv * 4 + s;        // 0..31, wave-uniform split
      const int cc  = c & 15;            // chunk within matrix
      const int tl  = cc >> 3;           // which 128-row tile (0/1)
      const int sub = cc & 7;            // 1KB sub-chunk
      const _Float16* g;
      int dst;
      if (c < 16) {
        g = xt + baseA + (size_t)(tl * 32 + kt) * TILE_HALFS + sub * 512 + lane * 8;
        dst = bufOff + cc * 512;
      } else {
        g = wt + baseB + (size_t)(tl * 32 + kt) * TILE_HALFS + sub * 512 + lane * 8;
        dst = bufOff + 8192 + cc * 512;
      }
      __builtin_amdgcn_global_load_lds(
          (const __attribute__((address_space(1))) void*)g,
          (__attribute__((address_space(3))) void*)(sm + dst), 16, 0, 0);
    }
  };

  auto compute = [&](int bufOff) {
    half8 af[4], bf[8];
#pragma unroll
    for (int f = 0; f < 4; f++)
      af[f] = *(const half8*)&sm[bufOff + ((wr >> 1) * 4 + kq) * 1024
                                 + ((wr & 1) * 64 + f * 16 + fm) * 8];
#pragma unroll
    for (int g = 0; g < 8; g++)
      bf[g] = *(const half8*)&sm[bufOff + 8192 + (wc * 4 + kq) * 1024
                                 + (g * 16 + fm) * 8];
    __builtin_amdgcn_s_setprio(1);
#pragma unroll
    for (int mt = 0; mt < 4; mt++)
#pragma unroll
      for (int nt = 0; nt < 8; nt++)
        acc[mt][nt] = __builtin_amdgcn_mfma_f32_16x16x32_f16(
            af[mt], bf[nt], acc[mt][nt], 0, 0, 0);
    __builtin_amdgcn_s_setprio(0);
  };

  stage(0, 0);
  stage(16384, 1);
  int o0 = 0, o1 = 16384, o2 = 32768;   // read buf, in-flight buf, free buf

#pragma unroll 1
  for (int kt = 0; kt < 32; kt++) {
    if (kt < 31) asm volatile("s_waitcnt vmcnt(4)" ::: "memory");
    else         asm volatile("s_waitcnt vmcnt(0)" ::: "memory");
    __builtin_amdgcn_s_barrier();
    __builtin_amdgcn_sched_barrier(0);
    if (kt + 2 < 32) stage(o2, kt + 2);  // o2 held kt-1: reads done pre-barrier
    compute(o0);
    const int t0 = o0; o0 = o1; o1 = o2; o2 = t0;
  }

  // ---- fused epilogue: sigmoid -> gather 4 fan-in values -> LUT contraction
#pragma unroll
  for (int nt = 0; nt < 8; nt++) {
    const int o = (nb * 256 + wc * 128 + nt * 16 + fm) >> 2;
    const float4* lt4 = (const float4*)(lut + (size_t)o * 16);
    const float4 L0 = lt4[0], L1 = lt4[1], L2 = lt4[2], L3 = lt4[3];
#pragma unroll
    for (int mt = 0; mt < 4; mt++) {
#pragma unroll
      for (int r = 0; r < 4; r++) {
        const float v  = acc[mt][nt][r];
        const float sv = 1.0f / (1.0f + __expf(-v));
        const float s1 = __shfl_down(sv, 1);
        const float s2 = __shfl_down(sv, 2);
        const float s3 = __shfl_down(sv, 3);
        if ((lane & 3) == 0) {
          const float s0 = sv;
          const float a0 = L0.x + (L2.x - L0.x) * s3;
          const float a1 = L0.y + (L2.y - L0.y) * s3;
          const float a2 = L0.z + (L2.z - L0.z) * s3;
          const float a3 = L0.w + (L2.w - L0.w) * s3;
          const float a4 = L1.x + (L3.x - L1.x) * s3;
          const float a5 = L1.y + (L3.y - L1.y) * s3;
          const float a6 = L1.z + (L3.z - L1.z) * s3;
          const float a7 = L1.w + (L3.w - L1.w) * s3;
          const float b0 = a0 + (a4 - a0) * s2;
          const float b1 = a1 + (a5 - a1) * s2;
          const float b2 = a2 + (a6 - a2) * s2;
          const float b3 = a3 + (a7 - a3) * s2;
          const float c0 = b0 + (b2 - b0) * s1;
          const float c1 = b1 + (b3 - b1) * s1;
          const float res = c0 + (c1 - c0) * s0;
          const int row = mb * 256 + wr * 64 + mt * 16 + (lane >> 4) * 4 + r;
          out[(size_t)row * O_DIM + o] = res;
        }
      }
    }
  }
}

// ---------------------------------------------------------------------------
extern "C" void kernel_launch(void* const* d_in, const int* in_sizes, int n_in,
                              void* d_out, int out_size, void* d_ws, size_t ws_size,
                              hipStream_t stream) {
  const float* x      = (const float*)d_in[0];  // (B, I)
  const float* logits = (const float*)d_in[1];  // (O, N, I)
  const float* lut    = (const float*)d_in[2];  // (O, 16)
  float* out          = (float*)d_out;          // (B, O)

  _Float16* wt = (_Float16*)d_ws;                                  // 8 MB tiled
  _Float16* xt = (_Float16*)d_ws + (size_t)ON_DIM * I_DIM;         // 8 MB tiled

  ltn_prep<<<2048, 256, 0, stream>>>(logits, x, wt, xt);
  ltn_gemm_lut<<<256, 512, 0, stream>>>(xt, wt, lut, out);
}